// Round 1
// baseline (463.117 us; speedup 1.0000x reference)
//
#include <hip/hip_runtime.h>
#include <math.h>

#define KK 15
#define K1 16
#define NN 4096
#define BSZ 128
#define NT 512
#define RPT 8          // rows per thread = NN/NT
#define NW 8           // waves per block
#define EPSI 0.1f
#define SMALLC 1e-20f
#define NITER 200
#define W2STRIDE 65536
#define OUT_A_ELEMS (BSZ * NN * KK)

// ---------- sortable float <-> uint encoding for atomic min/max ----------
__device__ __forceinline__ unsigned enc_f32(float f){
  unsigned u = __float_as_uint(f);
  return (u & 0x80000000u) ? ~u : (u | 0x80000000u);
}
__device__ __forceinline__ float dec_f32(unsigned e){
  unsigned u = (e & 0x80000000u) ? (e ^ 0x80000000u) : ~e;
  return __uint_as_float(u);
}

// ws layout (uint32): [0]=max_enc (init 0), [1]=neg_inf flag (init 0),
//                     [2]=norm^2 accum float (init 0), [3]=min_enc (init 0xFFFFFFFF)

__global__ void k_minmax(const float* __restrict__ s, unsigned* __restrict__ w){
  int tid = threadIdx.x;
  int base = blockIdx.x * 2048 + tid;
  float mx = -INFINITY, mn = INFINITY;
  unsigned neg = 0u;
  #pragma unroll
  for (int j = 0; j < 8; ++j){
    float v = s[base + j * 256];
    mx = fmaxf(mx, v);
    if (v == -INFINITY) neg = 1u;
    else mn = fminf(mn, v);
  }
  #pragma unroll
  for (int off = 32; off; off >>= 1){
    mx = fmaxf(mx, __shfl_xor(mx, off));
    mn = fminf(mn, __shfl_xor(mn, off));
    neg |= (unsigned)__shfl_xor((int)neg, off);
  }
  __shared__ float smx[4], smn[4];
  __shared__ unsigned sng[4];
  int lane = tid & 63, wv = tid >> 6;
  if (lane == 0){ smx[wv] = mx; smn[wv] = mn; sng[wv] = neg; }
  __syncthreads();
  if (tid == 0){
    for (int q = 1; q < 4; ++q){ mx = fmaxf(mx, smx[q]); mn = fminf(mn, smn[q]); neg |= sng[q]; }
    atomicMax(&w[0], enc_f32(mx));
    atomicMin(&w[3], enc_f32(mn));
    if (neg) atomicOr(&w[1], 1u);
  }
}

// ---------- 16-column lane-fold reduction ----------
// Input: p[16] per lane (partial per column). Output: each lane holds the
// wave-total of column fold_col(lane). Cost: 17 shuffles.
__device__ __forceinline__ int fold_col(int lane){
  int l = lane & 15;
  return ((l & 1) << 3) | ((l & 2) << 1) | ((l & 4) >> 1) | ((l & 8) >> 3);
}

__device__ __forceinline__ float wave_fold16(const float p[K1], int lane){
  float a[8];
  {
    const bool hi = (lane & 1) != 0;
    #pragma unroll
    for (int j = 0; j < 8; ++j){
      float send = hi ? p[j] : p[j + 8];
      float keep = hi ? p[j + 8] : p[j];
      a[j] = keep + __shfl_xor(send, 1);
    }
  }
  float bq[4];
  {
    const bool hi = (lane & 2) != 0;
    #pragma unroll
    for (int j = 0; j < 4; ++j){
      float send = hi ? a[j] : a[j + 4];
      float keep = hi ? a[j + 4] : a[j];
      bq[j] = keep + __shfl_xor(send, 2);
    }
  }
  float cq[2];
  {
    const bool hi = (lane & 4) != 0;
    #pragma unroll
    for (int j = 0; j < 2; ++j){
      float send = hi ? cq[0] * 0.0f + (j == 0 ? bq[0] : bq[1]) : bq[j + 2]; // placeholder, replaced below
      (void)send;
    }
    // (explicit to avoid any confusion)
    float s0 = hi ? bq[0] : bq[2];
    float s1 = hi ? bq[1] : bq[3];
    float k0 = hi ? bq[2] : bq[0];
    float k1 = hi ? bq[3] : bq[1];
    cq[0] = k0 + __shfl_xor(s0, 4);
    cq[1] = k1 + __shfl_xor(s1, 4);
  }
  float r;
  {
    const bool hi = (lane & 8) != 0;
    float send = hi ? cq[0] : cq[1];
    float keep = hi ? cq[1] : cq[0];
    r = keep + __shfl_xor(send, 8);
  }
  r += __shfl_xor(r, 16);
  r += __shfl_xor(r, 32);
  return r;
}

// Generic block fold: totals land in tb[0..15]; ends with __syncthreads().
__device__ __forceinline__ void block_fold16(const float p[K1], float* wb, float* tb,
                                             int lane, int wv, int tid){
  float r = wave_fold16(p, lane);
  if (lane < 16) wb[wv * K1 + fold_col(lane)] = r;
  __syncthreads();
  if (tid < 16){
    float t = 0.0f;
    #pragma unroll
    for (int q = 0; q < NW; ++q) t += wb[q * K1 + tid];
    tb[tid] = t;
  }
  __syncthreads();
}

__global__ __launch_bounds__(NT, 2) void k_main(
    const float* __restrict__ scores, const float* __restrict__ taup,
    const float* __restrict__ w1, const float* __restrict__ w2,
    float* __restrict__ out, unsigned* __restrict__ ws){
  const int b = blockIdx.x;
  const int tid = threadIdx.x;
  const int lane = tid & 63;
  const int wv = tid >> 6;

  __shared__ float s_lds[NN];
  __shared__ float scratch[NN];
  __shared__ float tk[KK];
  __shared__ __align__(16) float cbuf[K1];
  __shared__ __align__(16) float vbuf[K1];
  __shared__ float wbuf[NW * K1];
  __shared__ __align__(16) float xbuf[K1];
  __shared__ float rv[NW];
  __shared__ int ri[NW];

  // ---- global stats -> Cmax (exact closed form: max of (s-a)^2 is at data
  // extremes x anchor endpoints {0,15}, all of which are present values) ----
  const float smax = dec_f32(ws[0]);
  const float smin_raw = dec_f32(ws[3]);
  const bool has_neg = (ws[1] != 0u);
  const float filled = smin_raw - (smax - smin_raw);
  const float smin_eff = has_neg ? filled : smin_raw;
  const float cmax = fmaxf(fmaxf(smin_eff * smin_eff, smax * smax),
                           fmaxf((smin_eff - 15.0f) * (smin_eff - 15.0f),
                                 (smax - 15.0f) * (smax - 15.0f)));
  const float cinv = 1.0f / cmax;
  const float tauv = taup[0];
  const float inv_n = 1.0f / (float)NN;   // 2^-12, exact

  // ---- load s row (with -inf fill) ----
  #pragma unroll
  for (int j = 0; j < RPT; ++j){
    int i = tid + NT * j;
    float v = scores[(size_t)b * NN + i];
    if (v == -INFINITY) v = filled;
    s_lds[i] = v;
    scratch[i] = v;
  }
  __syncthreads();

  // ---- top-15 by iterative argmax (one-time) ----
  for (int t = 0; t < KK; ++t){
    float bv = -INFINITY; int bi = NN;
    #pragma unroll
    for (int j = 0; j < RPT; ++j){
      int i = tid + NT * j;
      float v = scratch[i];
      if (v > bv){ bv = v; bi = i; }
    }
    #pragma unroll
    for (int off = 32; off; off >>= 1){
      float ov = __shfl_xor(bv, off);
      int oi = __shfl_xor(bi, off);
      if (ov > bv || (ov == bv && oi < bi)){ bv = ov; bi = oi; }
    }
    if (lane == 0){ rv[wv] = bv; ri[wv] = bi; }
    __syncthreads();
    if (tid == 0){
      for (int q = 1; q < NW; ++q){
        if (rv[q] > bv || (rv[q] == bv && ri[q] < bi)){ bv = rv[q]; bi = ri[q]; }
      }
      tk[t] = bv;
      scratch[bi] = -INFINITY;
    }
    __syncthreads();
  }

  float p[K1];

  // ---- Gamma0 column sums (raw = sigmoid(-|tk_c - s|/tau) + SMALL) ----
  {
    float tkr[KK];
    #pragma unroll
    for (int c = 0; c < KK; ++c) tkr[c] = tk[c];
    #pragma unroll
    for (int c = 0; c < K1; ++c) p[c] = 0.0f;
    for (int j = 0; j < RPT; ++j){
      float si = s_lds[tid + NT * j];
      #pragma unroll
      for (int c = 0; c < KK; ++c){
        float z = fabsf(tkr[c] - si) / tauv;
        float raw = 1.0f / (1.0f + expf(z)) + SMALLC;
        p[c] += raw;
      }
    }
    block_fold16(p, wbuf, cbuf, lane, wv, tid);
  }

  // ---- warm start x_r = <b, weight2[r,:]> ; b = C + eps*log(Gamma0) ----
  {
    float tkr[KK], colr[KK];
    #pragma unroll
    for (int c = 0; c < KK; ++c){ tkr[c] = tk[c]; colr[c] = cbuf[c]; }
    #pragma unroll
    for (int c = 0; c < K1; ++c) p[c] = 0.0f;
    for (int j = 0; j < RPT; ++j){
      int i = tid + NT * j;
      float si = s_lds[i];
      float bb[K1];
      float rowpart = 0.0f;
      #pragma unroll
      for (int c = 0; c < KK; ++c){
        float d = si - (float)(KK - c);
        float Cc = d * d * cinv;
        float z = fabsf(tkr[c] - si) / tauv;
        float raw = 1.0f / (1.0f + expf(z)) + SMALLC;
        float g0 = (raw / colr[c]) * inv_n;
        rowpart += g0;
        bb[c] = Cc + EPSI * logf(g0);
      }
      {
        float Cc = si * si * cinv;  // anchor 0 for c=15
        float g0l = fminf(fmaxf(inv_n - rowpart, SMALLC), 1.0f - SMALLC);
        bb[KK] = Cc + EPSI * logf(g0l);
      }
      #pragma unroll
      for (int r = 0; r < 5; ++r){
        const float4* wp = (const float4*)(w2 + (size_t)r * W2STRIDE + (size_t)i * K1);
        float4 a0 = wp[0], a1 = wp[1], a2 = wp[2], a3 = wp[3];
        float acc = p[r];
        acc += bb[0] * a0.x + bb[1] * a0.y + bb[2] * a0.z + bb[3] * a0.w;
        acc += bb[4] * a1.x + bb[5] * a1.y + bb[6] * a1.z + bb[7] * a1.w;
        acc += bb[8] * a2.x + bb[9] * a2.y + bb[10] * a2.z + bb[11] * a2.w;
        acc += bb[12] * a3.x + bb[13] * a3.y + bb[14] * a3.z + bb[15] * a3.w;
        p[r] = acc;
      }
    }
    block_fold16(p, wbuf, xbuf, lane, wv, tid);
  }

  // ---- v init: g_c = sum_r x_r * w1[(N+c), r]; v = exp(g/eps); v[15] = 1 ----
  float v[K1];
  {
    float xv[5];
    #pragma unroll
    for (int r = 0; r < 5; ++r) xv[r] = xbuf[r];
    #pragma unroll
    for (int c = 0; c < KK; ++c){
      float g = 0.0f;
      #pragma unroll
      for (int r = 0; r < 5; ++r) g += xv[r] * w1[(size_t)(NN + c) * 5 + r];
      v[c] = expf(g * 10.0f);
    }
    v[KK] = 1.0f;
  }

  // ---- E = exp(-C/eps), kept entirely in VGPRs (8 rows x 16 cols) ----
  float E[RPT][K1];
  #pragma unroll
  for (int j = 0; j < RPT; ++j){
    float si = s_lds[tid + NT * j];
    #pragma unroll
    for (int c = 0; c < K1; ++c){
      float d = si - (float)(KK - c);
      float Cc = d * d * cinv;
      E[j][c] = expf(Cc * -10.0f);
    }
  }

  // ---- 200 Sinkhorn iterations in scaling form: pure FMA + one 16-col fold ----
  float u[RPT];
  const float nu15 = 4081.0f / 4096.0f;
  #pragma unroll 1
  for (int it = 0; it < NITER; ++it){
    #pragma unroll
    for (int c = 0; c < K1; ++c) p[c] = 0.0f;
    #pragma unroll
    for (int j = 0; j < RPT; ++j){
      float S = 0.0f;
      #pragma unroll
      for (int c = 0; c < K1; ++c) S = fmaf(E[j][c], v[c], S);
      float uu = inv_n * __builtin_amdgcn_rcpf(S);
      u[j] = uu;
      #pragma unroll
      for (int c = 0; c < K1; ++c) p[c] = fmaf(E[j][c], uu, p[c]);
    }
    float r = wave_fold16(p, lane);
    if (lane < 16) wbuf[wv * K1 + fold_col(lane)] = r;
    __syncthreads();
    if (tid < 16){
      float t = 0.0f;
      #pragma unroll
      for (int q = 0; q < NW; ++q) t += wbuf[q * K1 + tid];
      float nuc = (tid < KK) ? inv_n : nu15;
      vbuf[tid] = nuc * __builtin_amdgcn_rcpf(t);
    }
    __syncthreads();
    #pragma unroll
    for (int c = 0; c < K1; c += 4){
      float4 t4 = *((const float4*)(vbuf + c));
      v[c] = t4.x; v[c + 1] = t4.y; v[c + 2] = t4.z; v[c + 3] = t4.w;
    }
  }

  // ---- epilogue: A = Gamma[:, :, :15] * n; norm^2 partial over all 16 cols ----
  float nrm = 0.0f;
  {
    float tkr[KK], colr[KK];
    #pragma unroll
    for (int c = 0; c < KK; ++c){ tkr[c] = tk[c]; colr[c] = cbuf[c]; }
    for (int j = 0; j < RPT; ++j){
      int i = tid + NT * j;
      float si = s_lds[i];
      float uu = u[j];
      float rowpart = 0.0f;
      float* op = out + (size_t)(b * NN + i) * KK;
      #pragma unroll
      for (int c = 0; c < KK; ++c){
        float gam = E[j][c] * uu * v[c];
        float z = fabsf(tkr[c] - si) / tauv;
        float raw = 1.0f / (1.0f + expf(z)) + SMALLC;
        float g0 = (raw / colr[c]) * inv_n;
        rowpart += g0;
        float d = gam - g0;
        nrm += d * d;
        op[c] = gam * (float)NN;
      }
      {
        float gam = E[j][KK] * uu * v[KK];
        float g0l = fminf(fmaxf(inv_n - rowpart, SMALLC), 1.0f - SMALLC);
        float d = gam - g0l;
        nrm += d * d;
      }
    }
  }
  #pragma unroll
  for (int off = 32; off; off >>= 1) nrm += __shfl_xor(nrm, off);
  if (lane == 0) rv[wv] = nrm;
  __syncthreads();
  if (tid == 0){
    float t = 0.0f;
    for (int q = 0; q < NW; ++q) t += rv[q];
    atomicAdd(reinterpret_cast<float*>(ws) + 2, t);
  }
}

__global__ void k_sqrt(const unsigned* __restrict__ ws, float* __restrict__ out){
  const float* wf = reinterpret_cast<const float*>(ws);
  out[OUT_A_ELEMS] = sqrtf(wf[2]);
}

extern "C" void kernel_launch(void* const* d_in, const int* in_sizes, int n_in,
                              void* d_out, int out_size, void* d_ws, size_t ws_size,
                              hipStream_t stream){
  const float* scores = (const float*)d_in[0];
  const float* tau    = (const float*)d_in[1];
  const float* w1     = (const float*)d_in[2];  // (4111, 5) row-major
  const float* w2     = (const float*)d_in[3];  // (5, 65536) row-major
  float* out = (float*)d_out;
  unsigned* ws = (unsigned*)d_ws;

  // header: [max_enc=0][neg_flag=0][norm_acc=0.0f][min_enc=0xFFFFFFFF]
  hipMemsetAsync(ws, 0x00, 12, stream);
  hipMemsetAsync((char*)ws + 12, 0xFF, 4, stream);

  k_minmax<<<256, 256, 0, stream>>>(scores, ws);
  k_main<<<BSZ, NT, 0, stream>>>(scores, tau, w1, w2, out, ws);
  k_sqrt<<<1, 1, 0, stream>>>(ws, out);
}

// Round 2
// 456.042 us; speedup vs baseline: 1.0155x; 1.0155x over previous
//
#include <hip/hip_runtime.h>
#include <math.h>

#define KK 15
#define K1 16
#define NN 4096
#define BSZ 128
#define NT 512
#define RPT 8          // rows per thread = NN/NT
#define NPAIR 4        // packed row pairs per thread
#define NW 8           // waves per block
#define EPSI 0.1f
#define SMALLC 1e-20f
#define NITER 200
#define W2STRIDE 65536
#define OUT_A_ELEMS (BSZ * NN * KK)

typedef __attribute__((ext_vector_type(2))) float f2;
__device__ __forceinline__ f2 pk_fma(f2 a, f2 b, f2 c){
  return __builtin_elementwise_fma(a, b, c);   // -> v_pk_fma_f32
}

// ---------- sortable float <-> uint encoding for atomic min/max ----------
__device__ __forceinline__ unsigned enc_f32(float f){
  unsigned u = __float_as_uint(f);
  return (u & 0x80000000u) ? ~u : (u | 0x80000000u);
}
__device__ __forceinline__ float dec_f32(unsigned e){
  unsigned u = (e & 0x80000000u) ? (e ^ 0x80000000u) : ~e;
  return __uint_as_float(u);
}

// ws layout (uint32): [0]=max_enc (init 0), [1]=neg_inf flag (init 0),
//                     [2]=norm^2 accum float (init 0), [3]=min_enc (init 0xFFFFFFFF)

__global__ void k_minmax(const float* __restrict__ s, unsigned* __restrict__ w){
  int tid = threadIdx.x;
  int base = blockIdx.x * 2048 + tid;
  float mx = -INFINITY, mn = INFINITY;
  unsigned neg = 0u;
  #pragma unroll
  for (int j = 0; j < 8; ++j){
    float v = s[base + j * 256];
    mx = fmaxf(mx, v);
    if (v == -INFINITY) neg = 1u;
    else mn = fminf(mn, v);
  }
  #pragma unroll
  for (int off = 32; off; off >>= 1){
    mx = fmaxf(mx, __shfl_xor(mx, off));
    mn = fminf(mn, __shfl_xor(mn, off));
    neg |= (unsigned)__shfl_xor((int)neg, off);
  }
  __shared__ float smx[4], smn[4];
  __shared__ unsigned sng[4];
  int lane = tid & 63, wv = tid >> 6;
  if (lane == 0){ smx[wv] = mx; smn[wv] = mn; sng[wv] = neg; }
  __syncthreads();
  if (tid == 0){
    for (int q = 1; q < 4; ++q){ mx = fmaxf(mx, smx[q]); mn = fminf(mn, smn[q]); neg |= sng[q]; }
    atomicMax(&w[0], enc_f32(mx));
    atomicMin(&w[3], enc_f32(mn));
    if (neg) atomicOr(&w[1], 1u);
  }
}

// ---------- 16-column lane-fold reduction ----------
__device__ __forceinline__ int fold_col(int lane){
  int l = lane & 15;
  return ((l & 1) << 3) | ((l & 2) << 1) | ((l & 4) >> 1) | ((l & 8) >> 3);
}

__device__ __forceinline__ float wave_fold16(const float p[K1], int lane){
  float a[8];
  {
    const bool hi = (lane & 1) != 0;
    #pragma unroll
    for (int j = 0; j < 8; ++j){
      float send = hi ? p[j] : p[j + 8];
      float keep = hi ? p[j + 8] : p[j];
      a[j] = keep + __shfl_xor(send, 1);
    }
  }
  float bq[4];
  {
    const bool hi = (lane & 2) != 0;
    #pragma unroll
    for (int j = 0; j < 4; ++j){
      float send = hi ? a[j] : a[j + 4];
      float keep = hi ? a[j + 4] : a[j];
      bq[j] = keep + __shfl_xor(send, 2);
    }
  }
  float cq[2];
  {
    const bool hi = (lane & 4) != 0;
    float s0 = hi ? bq[0] : bq[2];
    float s1 = hi ? bq[1] : bq[3];
    float k0 = hi ? bq[2] : bq[0];
    float k1 = hi ? bq[3] : bq[1];
    cq[0] = k0 + __shfl_xor(s0, 4);
    cq[1] = k1 + __shfl_xor(s1, 4);
  }
  float r;
  {
    const bool hi = (lane & 8) != 0;
    float send = hi ? cq[0] : cq[1];
    float keep = hi ? cq[1] : cq[0];
    r = keep + __shfl_xor(send, 8);
  }
  r += __shfl_xor(r, 16);
  r += __shfl_xor(r, 32);
  return r;
}

__device__ __forceinline__ void block_fold16(const float p[K1], float* wb, float* tb,
                                             int lane, int wv, int tid){
  float r = wave_fold16(p, lane);
  if (lane < 16) wb[wv * K1 + fold_col(lane)] = r;
  __syncthreads();
  if (tid < 16){
    float t = 0.0f;
    #pragma unroll
    for (int q = 0; q < NW; ++q) t += wb[q * K1 + tid];
    tb[tid] = t;
  }
  __syncthreads();
}

__global__ __launch_bounds__(NT, 2) void k_main(
    const float* __restrict__ scores, const float* __restrict__ taup,
    const float* __restrict__ w1, const float* __restrict__ w2,
    float* __restrict__ out, unsigned* __restrict__ ws){
  const int b = blockIdx.x;
  const int tid = threadIdx.x;
  const int lane = tid & 63;
  const int wv = tid >> 6;

  __shared__ float s_lds[NN];
  __shared__ float scratch[NN];
  __shared__ float tk[KK];
  __shared__ __align__(16) float cbuf[K1];
  __shared__ __align__(16) float vbuf[K1];
  __shared__ float wbuf[NW * K1];
  __shared__ __align__(16) float xbuf[K1];
  __shared__ float rv[NW];
  __shared__ int ri[NW];

  // ---- global stats -> Cmax (exact closed form) ----
  const float smax = dec_f32(ws[0]);
  const float smin_raw = dec_f32(ws[3]);
  const bool has_neg = (ws[1] != 0u);
  const float filled = smin_raw - (smax - smin_raw);
  const float smin_eff = has_neg ? filled : smin_raw;
  const float cmax = fmaxf(fmaxf(smin_eff * smin_eff, smax * smax),
                           fmaxf((smin_eff - 15.0f) * (smin_eff - 15.0f),
                                 (smax - 15.0f) * (smax - 15.0f)));
  const float cinv = 1.0f / cmax;
  const float tauv = taup[0];
  const float inv_n = 1.0f / (float)NN;   // 2^-12, exact

  // ---- load s row (with -inf fill) ----
  #pragma unroll
  for (int j = 0; j < RPT; ++j){
    int i = tid + NT * j;
    float v = scores[(size_t)b * NN + i];
    if (v == -INFINITY) v = filled;
    s_lds[i] = v;
    scratch[i] = v;
  }
  __syncthreads();

  // ---- top-15 by iterative argmax ----
  for (int t = 0; t < KK; ++t){
    float bv = -INFINITY; int bi = NN;
    #pragma unroll
    for (int j = 0; j < RPT; ++j){
      int i = tid + NT * j;
      float v = scratch[i];
      if (v > bv){ bv = v; bi = i; }
    }
    #pragma unroll
    for (int off = 32; off; off >>= 1){
      float ov = __shfl_xor(bv, off);
      int oi = __shfl_xor(bi, off);
      if (ov > bv || (ov == bv && oi < bi)){ bv = ov; bi = oi; }
    }
    if (lane == 0){ rv[wv] = bv; ri[wv] = bi; }
    __syncthreads();
    if (tid == 0){
      for (int q = 1; q < NW; ++q){
        if (rv[q] > bv || (rv[q] == bv && ri[q] < bi)){ bv = rv[q]; bi = ri[q]; }
      }
      tk[t] = bv;
      scratch[bi] = -INFINITY;
    }
    __syncthreads();
  }

  // ---- Gamma0 column sums ----
  {
    float p[K1];
    float tkr[KK];
    #pragma unroll
    for (int c = 0; c < KK; ++c) tkr[c] = tk[c];
    #pragma unroll
    for (int c = 0; c < K1; ++c) p[c] = 0.0f;
    for (int j = 0; j < RPT; ++j){
      float si = s_lds[tid + NT * j];
      #pragma unroll
      for (int c = 0; c < KK; ++c){
        float z = fabsf(tkr[c] - si) / tauv;
        float raw = 1.0f / (1.0f + expf(z)) + SMALLC;
        p[c] += raw;
      }
    }
    block_fold16(p, wbuf, cbuf, lane, wv, tid);
  }

  // ---- warm start x_r = <b, weight2[r,:]> ----
  {
    float p[K1];
    float tkr[KK], colr[KK];
    #pragma unroll
    for (int c = 0; c < KK; ++c){ tkr[c] = tk[c]; colr[c] = cbuf[c]; }
    #pragma unroll
    for (int c = 0; c < K1; ++c) p[c] = 0.0f;
    for (int j = 0; j < RPT; ++j){
      int i = tid + NT * j;
      float si = s_lds[i];
      float bb[K1];
      float rowpart = 0.0f;
      #pragma unroll
      for (int c = 0; c < KK; ++c){
        float d = si - (float)(KK - c);
        float Cc = d * d * cinv;
        float z = fabsf(tkr[c] - si) / tauv;
        float raw = 1.0f / (1.0f + expf(z)) + SMALLC;
        float g0 = (raw / colr[c]) * inv_n;
        rowpart += g0;
        bb[c] = Cc + EPSI * logf(g0);
      }
      {
        float Cc = si * si * cinv;  // anchor 0 for c=15
        float g0l = fminf(fmaxf(inv_n - rowpart, SMALLC), 1.0f - SMALLC);
        bb[KK] = Cc + EPSI * logf(g0l);
      }
      #pragma unroll
      for (int r = 0; r < 5; ++r){
        const float4* wp = (const float4*)(w2 + (size_t)r * W2STRIDE + (size_t)i * K1);
        float4 a0 = wp[0], a1 = wp[1], a2 = wp[2], a3 = wp[3];
        float acc = p[r];
        acc += bb[0] * a0.x + bb[1] * a0.y + bb[2] * a0.z + bb[3] * a0.w;
        acc += bb[4] * a1.x + bb[5] * a1.y + bb[6] * a1.z + bb[7] * a1.w;
        acc += bb[8] * a2.x + bb[9] * a2.y + bb[10] * a2.z + bb[11] * a2.w;
        acc += bb[12] * a3.x + bb[13] * a3.y + bb[14] * a3.z + bb[15] * a3.w;
        p[r] = acc;
      }
    }
    block_fold16(p, wbuf, xbuf, lane, wv, tid);
  }

  // ---- vt init: vt_c = B_c * exp(g_c/eps); vt[15] = 1 ----
  // Factorization: E[j][c] = P_j * x_j^c * B_c with x_j = exp(-20 s_j/cmax),
  // B_c = exp(-10 (15-c)^2/cmax). P and B cancel from the Sinkhorn update
  // (t = P*u, vt = B*v) and from Gamma = x^c * t * vt.
  float vt[K1];
  {
    float xv[5];
    #pragma unroll
    for (int r = 0; r < 5; ++r) xv[r] = xbuf[r];
    #pragma unroll
    for (int c = 0; c < KK; ++c){
      float g = 0.0f;
      #pragma unroll
      for (int r = 0; r < 5; ++r) g += xv[r] * w1[(size_t)(NN + c) * 5 + r];
      float Bc = expf(-10.0f * cinv * (float)((KK - c) * (KK - c)));
      vt[c] = Bc * expf(g * 10.0f);
    }
    vt[KK] = 1.0f;
  }

  // ---- x per row (1 VGPR/row instead of 16 for E) ----
  float xr[RPT];
  #pragma unroll
  for (int j = 0; j < RPT; ++j){
    float si = s_lds[tid + NT * j];
    xr[j] = expf(si * (-20.0f * cinv));
  }
  f2 x2[NPAIR];
  #pragma unroll
  for (int q = 0; q < NPAIR; ++q){ x2[q].x = xr[2 * q]; x2[q].y = xr[2 * q + 1]; }

  // ---- 200 Sinkhorn iterations: packed Horner + packed power chain ----
  f2 u2[NPAIR];                       // t_j of the most recent row update
  const float nu15 = 4081.0f / 4096.0f;
  #pragma unroll 1
  for (int it = 0; it < NITER; ++it){
    // row sums H_j = sum_c x_j^c * vt_c  (Horner, packed over row pairs)
    f2 H[NPAIR];
    {
      f2 vl; vl.x = vt[KK]; vl.y = vt[KK];
      #pragma unroll
      for (int q = 0; q < NPAIR; ++q) H[q] = vl;
    }
    #pragma unroll
    for (int c = KK - 1; c >= 0; --c){
      f2 vc; vc.x = vt[c]; vc.y = vt[c];
      #pragma unroll
      for (int q = 0; q < NPAIR; ++q) H[q] = pk_fma(H[q], x2[q], vc);
    }
    #pragma unroll
    for (int q = 0; q < NPAIR; ++q){
      u2[q].x = inv_n * __builtin_amdgcn_rcpf(H[q].x);
      u2[q].y = inv_n * __builtin_amdgcn_rcpf(H[q].y);
    }
    // column partials p_c = sum_j x_j^c * t_j  (packed power chain)
    f2 P2[K1];
    #pragma unroll
    for (int q = 0; q < NPAIR; ++q){
      f2 pw = u2[q];
      #pragma unroll
      for (int c = 0; c < K1; ++c){
        if (q == 0) P2[c] = pw; else P2[c] += pw;
        if (c < KK) pw = pw * x2[q];
      }
    }
    float p[K1];
    #pragma unroll
    for (int c = 0; c < K1; ++c) p[c] = P2[c].x + P2[c].y;

    float r = wave_fold16(p, lane);
    if (lane < 16) wbuf[wv * K1 + fold_col(lane)] = r;
    __syncthreads();
    if (tid < 16){
      float t = 0.0f;
      #pragma unroll
      for (int q = 0; q < NW; ++q) t += wbuf[q * K1 + tid];
      float nuc = (tid < KK) ? inv_n : nu15;
      vbuf[tid] = nuc * __builtin_amdgcn_rcpf(t);
    }
    __syncthreads();
    #pragma unroll
    for (int c = 0; c < K1; c += 4){
      float4 t4 = *((const float4*)(vbuf + c));
      vt[c] = t4.x; vt[c + 1] = t4.y; vt[c + 2] = t4.z; vt[c + 3] = t4.w;
    }
  }

  // ---- epilogue: Gamma = x^c * t * vt; A = Gamma[:, :, :15] * n; norm^2 ----
  float nrm = 0.0f;
  {
    float tkr[KK], colr[KK];
    #pragma unroll
    for (int c = 0; c < KK; ++c){ tkr[c] = tk[c]; colr[c] = cbuf[c]; }
    for (int j = 0; j < RPT; ++j){
      int i = tid + NT * j;
      float si = s_lds[i];
      float tt = (j & 1) ? u2[j >> 1].y : u2[j >> 1].x;
      float xj = xr[j];
      float pw = tt;
      float rowpart = 0.0f;
      float* op = out + (size_t)(b * NN + i) * KK;
      #pragma unroll
      for (int c = 0; c < KK; ++c){
        float gam = pw * vt[c];
        pw *= xj;
        float z = fabsf(tkr[c] - si) / tauv;
        float raw = 1.0f / (1.0f + expf(z)) + SMALLC;
        float g0 = (raw / colr[c]) * inv_n;
        rowpart += g0;
        float d = gam - g0;
        nrm += d * d;
        op[c] = gam * (float)NN;
      }
      {
        float gam = pw * vt[KK];   // pw = t * x^15 here
        float g0l = fminf(fmaxf(inv_n - rowpart, SMALLC), 1.0f - SMALLC);
        float d = gam - g0l;
        nrm += d * d;
      }
    }
  }
  #pragma unroll
  for (int off = 32; off; off >>= 1) nrm += __shfl_xor(nrm, off);
  if (lane == 0) rv[wv] = nrm;
  __syncthreads();
  if (tid == 0){
    float t = 0.0f;
    for (int q = 0; q < NW; ++q) t += rv[q];
    atomicAdd(reinterpret_cast<float*>(ws) + 2, t);
  }
}

__global__ void k_sqrt(const unsigned* __restrict__ ws, float* __restrict__ out){
  const float* wf = reinterpret_cast<const float*>(ws);
  out[OUT_A_ELEMS] = sqrtf(wf[2]);
}

extern "C" void kernel_launch(void* const* d_in, const int* in_sizes, int n_in,
                              void* d_out, int out_size, void* d_ws, size_t ws_size,
                              hipStream_t stream){
  const float* scores = (const float*)d_in[0];
  const float* tau    = (const float*)d_in[1];
  const float* w1     = (const float*)d_in[2];  // (4111, 5) row-major
  const float* w2     = (const float*)d_in[3];  // (5, 65536) row-major
  float* out = (float*)d_out;
  unsigned* ws = (unsigned*)d_ws;

  // header: [max_enc=0][neg_flag=0][norm_acc=0.0f][min_enc=0xFFFFFFFF]
  hipMemsetAsync(ws, 0x00, 12, stream);
  hipMemsetAsync((char*)ws + 12, 0xFF, 4, stream);

  k_minmax<<<256, 256, 0, stream>>>(scores, ws);
  k_main<<<BSZ, NT, 0, stream>>>(scores, tau, w1, w2, out, ws);
  k_sqrt<<<1, 1, 0, stream>>>(ws, out);
}